// Round 13
// baseline (441.168 us; speedup 1.0000x reference)
//
#include <hip/hip_runtime.h>
#include <stdint.h>
#include <stddef.h>

// QuantizedColumnParallel: y[4096,16384] = x[4096,4096] @ (wq[16384,4096]*scale)^T + bias
// R13: R6 structure (best: 333us GEMM; 5 schedules all ~330-345 -> pipes sum) with
// mfma_i32_32x32x32_i8 (4404 vs 3944 TOPS, half the MFMA insts). Bank arithmetic:
// 32-lane-per-chunk reads spread 8 lanes per (parity,chunk) bank-group = 32B/bank
// = 8 bank-cycles = minimum for a 1024B wave-read -> existing swizzle stays optimal.
// C/D map: col=lane&31, row=(reg&3)+8*(reg>>2)+4*(lane>>5) (m74/m101, dtype-indep).
// Everything else (triple buffer, stage t+2, vmcnt(4), conversions) unchanged.

#define M_TOT 4096
#define N_TOT 16384
#define K_TOT 4096
#define NT    64          // K-tiles

typedef __attribute__((ext_vector_type(4)))  int      v4i;
typedef __attribute__((ext_vector_type(16))) int      v16i;
typedef __attribute__((ext_vector_type(8)))  _Float16 f16x8;
typedef __attribute__((ext_vector_type(4)))  float    f32x4;

#define GLOAD_LDS16(g, l) __builtin_amdgcn_global_load_lds(                  \
    (const __attribute__((address_space(1))) void*)(g),                      \
    (__attribute__((address_space(3))) void*)(l), 16, 0, 0)

// ---------------- conversion pre-passes ----------------

__global__ __launch_bounds__(256) void cvt_x_i8(const float* __restrict__ x,
                                                signed char* __restrict__ o,
                                                float* __restrict__ sx) {
  const int row = blockIdx.x;
  const int tid = threadIdx.x;
  const float* xr = x + (size_t)row * K_TOT;
  float4 v[4];
  float mx = 0.f;
#pragma unroll
  for (int j = 0; j < 4; ++j) {
    v[j] = ((const float4*)xr)[tid * 4 + j];
    mx = fmaxf(mx, fmaxf(fmaxf(fabsf(v[j].x), fabsf(v[j].y)),
                         fmaxf(fabsf(v[j].z), fabsf(v[j].w))));
  }
#pragma unroll
  for (int off = 32; off; off >>= 1) mx = fmaxf(mx, __shfl_xor(mx, off));
  __shared__ float wm[4];
  if ((tid & 63) == 0) wm[tid >> 6] = mx;
  __syncthreads();
  const float m4 = fmaxf(fmaxf(wm[0], wm[1]), fmaxf(wm[2], wm[3]));
  const float smax = fmaxf(m4, 1e-6f);
  const float inv  = 127.0f / smax;
  if (tid == 0) sx[row] = smax / 127.0f;
  int p[4];
#pragma unroll
  for (int j = 0; j < 4; ++j) {
    int q0 = (int)rintf(v[j].x * inv), q1 = (int)rintf(v[j].y * inv);
    int q2 = (int)rintf(v[j].z * inv), q3 = (int)rintf(v[j].w * inv);
    q0 = max(-127, min(127, q0)); q1 = max(-127, min(127, q1));
    q2 = max(-127, min(127, q2)); q3 = max(-127, min(127, q3));
    p[j] = (q0 & 255) | ((q1 & 255) << 8) | ((q2 & 255) << 16) | (q3 << 24);
  }
  ((int4*)(o + (size_t)row * K_TOT))[tid] = make_int4(p[0], p[1], p[2], p[3]);
}

__global__ __launch_bounds__(256) void cvt_w_i8(const int* __restrict__ w,
                                                signed char* __restrict__ o, int n16) {
  const int stride = gridDim.x * blockDim.x;
  for (int i = blockIdx.x * blockDim.x + threadIdx.x; i < n16; i += stride) {
    int p[4];
#pragma unroll
    for (int j = 0; j < 4; ++j) {
      int4 a = ((const int4*)w)[i * 4 + j];
      p[j] = (a.x & 255) | ((a.y & 255) << 8) | ((a.z & 255) << 16) | (a.w << 24);
    }
    ((int4*)o)[i] = make_int4(p[0], p[1], p[2], p[3]);
  }
}

// ---------------- i8 GEMM: 256^2, 32x32x32 MFMA, triple-buffered ----------------

__device__ __forceinline__ void stage_i8(const signed char* __restrict__ g,
                                         size_t kbyte, signed char* l, int tid) {
#pragma unroll
  for (int j = 0; j < 2; ++j) {
    const int ci  = j * 512 + tid;       // 0..1023 16B-chunks
    const int row = ci >> 2;             // 0..255
    const int sc  = (ci & 3) ^ ((row >> 1) & 3);
    GLOAD_LDS16(g + (size_t)row * K_TOT + kbyte + sc * 16, l + ci * 16);
  }
}

// Swizzled fragment read: row r, 16B chunk c (0..3) of the 64B row.
__device__ __forceinline__ v4i fragi(const signed char* region, int r, int c) {
  return *(const v4i*)(region + r * 64 + ((c ^ ((r >> 1) & 3)) << 4));
}

#define BAR()    __builtin_amdgcn_s_barrier()

__global__ __launch_bounds__(512, 2) void gemm_i8(
    const signed char* __restrict__ A8, const signed char* __restrict__ B8,
    const float* __restrict__ sx, const float* __restrict__ scale_p,
    const float* __restrict__ bias, float* __restrict__ out)
{
  // lds[buf(3)][A=0|B=1][256*64 bytes] = 96 KiB -> 1 block/CU
  __shared__ __align__(16) signed char lds[3][2][16384];

  const int tid  = threadIdx.x;
  const int lane = tid & 63;
  const int wave = tid >> 6;
  const int wr  = wave >> 2;           // 0..1 (M)
  const int wc  = wave & 3;            // 0..3 (N)
  const int l31 = lane & 31;           // row/col within 32-subtile
  const int hi2 = lane >> 5;           // k-half of K=32 (16B)

  // XCD-aware swizzle: 1024 wg, 8 XCDs, 128 contiguous per XCD; bm fast.
  const int bid = blockIdx.x;
  const int wg  = (bid & 7) * 128 + (bid >> 3);
  const int bm  = wg & 15;
  const int bn  = wg >> 4;
  const int arow0 = bm * 256;
  const int brow0 = bn * 256;

  const signed char* Ag = A8 + (size_t)arow0 * K_TOT;
  const signed char* Bg = B8 + (size_t)brow0 * K_TOT;

  v16i acc[4][2];
#pragma unroll
  for (int mi = 0; mi < 4; ++mi)
#pragma unroll
    for (int ni = 0; ni < 2; ++ni)
#pragma unroll
      for (int j = 0; j < 16; ++j)
        acc[mi][ni][j] = 0;

  // ---- prologue: stage tiles 0,1; vmcnt(4) => tile0 landed, tile1 in flight.
  stage_i8(Ag, 0,  &lds[0][0][0], tid);
  stage_i8(Bg, 0,  &lds[0][1][0], tid);
  stage_i8(Ag, 64, &lds[1][0][0], tid);
  stage_i8(Bg, 64, &lds[1][1][0], tid);
  asm volatile("s_waitcnt vmcnt(4)" ::: "memory");
  BAR();

  for (int t = 0; t < NT; ++t) {
    const signed char* At = &lds[t % 3][0][0];
    const signed char* Bt = &lds[t % 3][1][0];

    // Stage t+2 first (latency starts earliest).
    if (t + 2 < NT) {
      const size_t k2 = (size_t)(t + 2) * 64;
      stage_i8(Ag, k2, &lds[(t + 2) % 3][0][0], tid);
      stage_i8(Bg, k2, &lds[(t + 2) % 3][1][0], tid);
    }

    // 12 frag reads (8 A + 4 B) + 16 MFMAs of 32x32x32.
    // A operand: row = l31 within 32-subtile, k-bytes = ks*32 + hi2*16.
    v4i af[4][2], bf[2][2];
#pragma unroll
    for (int mi = 0; mi < 4; ++mi)
#pragma unroll
      for (int ks = 0; ks < 2; ++ks)
        af[mi][ks] = fragi(At, wr * 128 + mi * 32 + l31, ks * 2 + hi2);
#pragma unroll
    for (int ni = 0; ni < 2; ++ni)
#pragma unroll
      for (int ks = 0; ks < 2; ++ks)
        bf[ni][ks] = fragi(Bt, wc * 64 + ni * 32 + l31, ks * 2 + hi2);
#pragma unroll
    for (int mi = 0; mi < 4; ++mi)
#pragma unroll
      for (int ni = 0; ni < 2; ++ni)
#pragma unroll
        for (int ks = 0; ks < 2; ++ks)
          acc[mi][ni] = __builtin_amdgcn_mfma_i32_32x32x32_i8(
              af[mi][ks], bf[ni][ks], acc[mi][ni], 0, 0, 0);

    // Publish t+1 (oldest 4 landed), keep t+2 (youngest 4) in flight.
    if (t < NT - 2) asm volatile("s_waitcnt vmcnt(4)" ::: "memory");
    else            asm volatile("s_waitcnt vmcnt(0)" ::: "memory");
    BAR();
  }

  // ---- epilogue: y = acc * (sx[row]*scale) + bias.
  // 32x32 C/D map (dtype-indep): col=lane&31, row=(reg&3)+8*(reg>>2)+4*(lane>>5).
  const float s = scale_p[0];
  float bv[2];
#pragma unroll
  for (int ni = 0; ni < 2; ++ni) bv[ni] = bias[brow0 + wc * 64 + ni * 32 + l31];
#pragma unroll
  for (int mi = 0; mi < 4; ++mi) {
    const int rbase = arow0 + wr * 128 + mi * 32 + 4 * hi2;
    float sc16[16];
#pragma unroll
    for (int j = 0; j < 16; ++j)
      sc16[j] = sx[rbase + (j & 3) + 8 * (j >> 2)] * s;
#pragma unroll
    for (int ni = 0; ni < 2; ++ni) {
      const int col = brow0 + wc * 64 + ni * 32 + l31;
      const v16i v = acc[mi][ni];
#pragma unroll
      for (int j = 0; j < 16; ++j) {
        const int row = rbase + (j & 3) + 8 * (j >> 2);
        out[(size_t)row * N_TOT + col] = (float)v[j] * sc16[j] + bv[ni];
      }
    }
  }
}

// ---------------- fallback (no workspace): f16 DIRECT 128^2 kernel ----------------

__global__ __launch_bounds__(256) void gemm_direct(
    const float* __restrict__ Xf, const int* __restrict__ Wq,
    const float* __restrict__ scale_p, const float* __restrict__ bias,
    float* __restrict__ out)
{
  __shared__ _Float16 ldsA[128 * 64];
  __shared__ _Float16 ldsB[128 * 64];
  const int tid = threadIdx.x, lane = tid & 63, wave = tid >> 6;
  const int wr = wave >> 1, wc = wave & 1;
  const int bid = blockIdx.x;
  const int wg  = (bid & 7) * 512 + (bid >> 3);
  const int arow0 = (wg & 31) * 128, brow0 = (wg >> 5) * 128;
  f32x4 acc[4][4];
#pragma unroll
  for (int m = 0; m < 4; ++m)
#pragma unroll
    for (int n = 0; n < 4; ++n) acc[m][n] = (f32x4){0.f, 0.f, 0.f, 0.f};
  const int srow = tid >> 3, schunk = tid & 7;
  const int lr = lane & 15, hi = lane >> 4;
  for (int kt = 0; kt < K_TOT / 64; ++kt) {
    const size_t kbase = (size_t)kt * 64;
    __syncthreads();
#pragma unroll
    for (int i = 0; i < 4; ++i) {
      const int row = i * 32 + srow;
      const int p = schunk ^ (row & 7);
      const float* gx = Xf + (size_t)(arow0 + row) * K_TOT + kbase + schunk * 8;
      const int*   gw = Wq + (size_t)(brow0 + row) * K_TOT + kbase + schunk * 8;
      float4 x0 = ((const float4*)gx)[0];
      float4 x1 = ((const float4*)gx)[1];
      int4   w0 = ((const int4*)gw)[0];
      int4   w1 = ((const int4*)gw)[1];
      f16x8 ha = { (_Float16)x0.x, (_Float16)x0.y, (_Float16)x0.z, (_Float16)x0.w,
                   (_Float16)x1.x, (_Float16)x1.y, (_Float16)x1.z, (_Float16)x1.w };
      f16x8 hb = { (_Float16)w0.x, (_Float16)w0.y, (_Float16)w0.z, (_Float16)w0.w,
                   (_Float16)w1.x, (_Float16)w1.y, (_Float16)w1.z, (_Float16)w1.w };
      *(f16x8*)(ldsA + row * 64 + p * 8) = ha;
      *(f16x8*)(ldsB + row * 64 + p * 8) = hb;
    }
    __syncthreads();
#pragma unroll
    for (int s2 = 0; s2 < 2; ++s2) {
      f16x8 af2[4], bf2[4];
#pragma unroll
      for (int m = 0; m < 4; ++m) {
        const int r = wr * 64 + m * 16 + lr;
        af2[m] = *(const f16x8*)(ldsA + r * 64 + (((s2 * 4 + hi) ^ (r & 7)) * 8));
      }
#pragma unroll
      for (int n = 0; n < 4; ++n) {
        const int r = wc * 64 + n * 16 + lr;
        bf2[n] = *(const f16x8*)(ldsB + r * 64 + (((s2 * 4 + hi) ^ (r & 7)) * 8));
      }
#pragma unroll
      for (int m = 0; m < 4; ++m)
#pragma unroll
        for (int n = 0; n < 4; ++n)
          acc[m][n] = __builtin_amdgcn_mfma_f32_16x16x32_f16(af2[m], bf2[n], acc[m][n], 0, 0, 0);
    }
  }
  const float s = scale_p[0];
#pragma unroll
  for (int n = 0; n < 4; ++n) {
    const int col = brow0 + wc * 64 + n * 16 + lr;
    const float bvv = bias[col];
#pragma unroll
    for (int m = 0; m < 4; ++m) {
      const int row0 = arow0 + wr * 64 + m * 16 + hi * 4;
      const f32x4 v = acc[m][n];
#pragma unroll
      for (int j = 0; j < 4; ++j)
        out[(size_t)(row0 + j) * N_TOT + col] = v[j] * s + bvv;
    }
  }
}

// ---------------- launch ----------------

extern "C" void kernel_launch(void* const* d_in, const int* in_sizes, int n_in,
                              void* d_out, int out_size, void* d_ws, size_t ws_size,
                              hipStream_t stream) {
  const float* x     = (const float*)d_in[0];
  const int*   wq    = (const int*)d_in[1];
  const float* scale = (const float*)d_in[2];
  const float* bias  = (const float*)d_in[3];
  float*       out   = (float*)d_out;

  const size_t nA = (size_t)M_TOT * K_TOT;   // 16.7M
  const size_t nB = (size_t)N_TOT * K_TOT;   // 67.1M
  const size_t need = nA + nB + M_TOT * sizeof(float);  // ~84 MiB

  if (ws_size >= need) {
    signed char* A8 = (signed char*)d_ws;
    signed char* B8 = A8 + nA;
    float*       sx = (float*)(B8 + nB);
    cvt_x_i8<<<M_TOT, 256, 0, stream>>>(x, A8, sx);
    cvt_w_i8<<<2048, 256, 0, stream>>>(wq, B8, (int)(nB / 16));
    gemm_i8<<<(M_TOT / 256) * (N_TOT / 256), 512, 0, stream>>>(A8, B8, sx, scale, bias, out);
  } else {
    gemm_direct<<<(M_TOT / 128) * (N_TOT / 128), 256, 0, stream>>>(x, wq, scale, bias, out);
  }
}

// Round 14
// 410.675 us; speedup vs baseline: 1.0743x; 1.0743x over previous
//
#include <hip/hip_runtime.h>
#include <stdint.h>
#include <stddef.h>

// QuantizedColumnParallel: y[4096,16384] = x[4096,4096] @ (wq[16384,4096]*scale)^T + bias
// R14: R6 16x16x64 structure (R13's 32x32 introduced 2.5e7 bank conflicts -> reverted)
// with BK=128: 2 buffers x 64KB = 128 KB LDS, ONE vmcnt(0)+barrier per 128-K tile
// (32 iters) instead of per 64-K (64 iters) -> sync term halved. Staging loads issue
// at tile top, drain ~5000 cyc later => vmcnt(0) nearly free (>> 900 cyc HBM).
// 128B rows use the m214-proven swizzle chunk ^= (row&7) (8 chunks of 16B), both
// sides (rule #21). Everything else (i8 numerics, epilogue, cvt passes) unchanged.

#define M_TOT 4096
#define N_TOT 16384
#define K_TOT 4096
#define NT    32          // K-tiles of 128

typedef __attribute__((ext_vector_type(4))) int      v4i;
typedef __attribute__((ext_vector_type(8))) _Float16 f16x8;
typedef __attribute__((ext_vector_type(4))) float    f32x4;

#define GLOAD_LDS16(g, l) __builtin_amdgcn_global_load_lds(                  \
    (const __attribute__((address_space(1))) void*)(g),                      \
    (__attribute__((address_space(3))) void*)(l), 16, 0, 0)

// ---------------- conversion pre-passes ----------------

__global__ __launch_bounds__(256) void cvt_x_i8(const float* __restrict__ x,
                                                signed char* __restrict__ o,
                                                float* __restrict__ sx) {
  const int row = blockIdx.x;
  const int tid = threadIdx.x;
  const float* xr = x + (size_t)row * K_TOT;
  float4 v[4];
  float mx = 0.f;
#pragma unroll
  for (int j = 0; j < 4; ++j) {
    v[j] = ((const float4*)xr)[tid * 4 + j];
    mx = fmaxf(mx, fmaxf(fmaxf(fabsf(v[j].x), fabsf(v[j].y)),
                         fmaxf(fabsf(v[j].z), fabsf(v[j].w))));
  }
#pragma unroll
  for (int off = 32; off; off >>= 1) mx = fmaxf(mx, __shfl_xor(mx, off));
  __shared__ float wm[4];
  if ((tid & 63) == 0) wm[tid >> 6] = mx;
  __syncthreads();
  const float m4 = fmaxf(fmaxf(wm[0], wm[1]), fmaxf(wm[2], wm[3]));
  const float smax = fmaxf(m4, 1e-6f);
  const float inv  = 127.0f / smax;
  if (tid == 0) sx[row] = smax / 127.0f;
  int p[4];
#pragma unroll
  for (int j = 0; j < 4; ++j) {
    int q0 = (int)rintf(v[j].x * inv), q1 = (int)rintf(v[j].y * inv);
    int q2 = (int)rintf(v[j].z * inv), q3 = (int)rintf(v[j].w * inv);
    q0 = max(-127, min(127, q0)); q1 = max(-127, min(127, q1));
    q2 = max(-127, min(127, q2)); q3 = max(-127, min(127, q3));
    p[j] = (q0 & 255) | ((q1 & 255) << 8) | ((q2 & 255) << 16) | (q3 << 24);
  }
  ((int4*)(o + (size_t)row * K_TOT))[tid] = make_int4(p[0], p[1], p[2], p[3]);
}

__global__ __launch_bounds__(256) void cvt_w_i8(const int* __restrict__ w,
                                                signed char* __restrict__ o, int n16) {
  const int stride = gridDim.x * blockDim.x;
  for (int i = blockIdx.x * blockDim.x + threadIdx.x; i < n16; i += stride) {
    int p[4];
#pragma unroll
    for (int j = 0; j < 4; ++j) {
      int4 a = ((const int4*)w)[i * 4 + j];
      p[j] = (a.x & 255) | ((a.y & 255) << 8) | ((a.z & 255) << 16) | (a.w << 24);
    }
    ((int4*)o)[i] = make_int4(p[0], p[1], p[2], p[3]);
  }
}

// ---------------- i8 GEMM: 256^2 tile, BK=128, 2 buffers, 1 sync/tile ----------------

// Stage one 256x128-byte region (32 KiB): 4 x global_load_lds(16B)/thread.
// LDS dest linear; swizzle chunk^(row&7) applied on the GLOBAL source chunk
// (rule #21). 128B rows span the full bank space: within a 16-lane frag-read
// group the XOR spreads 16 lanes over 8 slots x 2 = 2-way aliasing = free (m136;
// same pattern as m214's [64][128] fix, +89% there).
__device__ __forceinline__ void stage128(const signed char* __restrict__ g,
                                         size_t kbyte, signed char* l, int tid) {
#pragma unroll
  for (int j = 0; j < 4; ++j) {
    const int ci  = j * 512 + tid;       // 0..2047 16B-chunks
    const int row = ci >> 3;             // 0..255
    const int sc  = (ci & 7) ^ (row & 7);
    GLOAD_LDS16(g + (size_t)row * K_TOT + kbyte + sc * 16, l + ci * 16);
  }
}

// Swizzled fragment read: row r, 16B chunk ch (0..7) of the 128B row.
__device__ __forceinline__ v4i frag128(const signed char* region, int r, int ch) {
  return *(const v4i*)(region + r * 128 + ((ch ^ (r & 7)) << 4));
}

#define BAR()    __builtin_amdgcn_s_barrier()

__global__ __launch_bounds__(512, 2) void gemm_i8(
    const signed char* __restrict__ A8, const signed char* __restrict__ B8,
    const float* __restrict__ sx, const float* __restrict__ scale_p,
    const float* __restrict__ bias, float* __restrict__ out)
{
  // lds[buf(2)][A=0|B=1][256*128 bytes] = 128 KiB -> 1 block/CU
  __shared__ __align__(16) signed char lds[2][2][32768];

  const int tid  = threadIdx.x;
  const int lane = tid & 63;
  const int wave = tid >> 6;
  const int wr = wave >> 2;            // 0..1 (M)
  const int wc = wave & 3;             // 0..3 (N)
  const int lr = lane & 15;
  const int hi = lane >> 4;            // 0..3 -> 16B sub-chunk of K=64

  // XCD-aware swizzle: 1024 wg, 8 XCDs, 128 contiguous per XCD; bm fast.
  const int bid = blockIdx.x;
  const int wg  = (bid & 7) * 128 + (bid >> 3);
  const int bm  = wg & 15;
  const int bn  = wg >> 4;
  const int arow0 = bm * 256;
  const int brow0 = bn * 256;

  const signed char* Ag = A8 + (size_t)arow0 * K_TOT;
  const signed char* Bg = B8 + (size_t)brow0 * K_TOT;

  v4i acc[8][4];
#pragma unroll
  for (int m = 0; m < 8; ++m)
#pragma unroll
    for (int n = 0; n < 4; ++n)
      acc[m][n] = (v4i){0, 0, 0, 0};

  // ---- prologue: stage tile0 -> buf0; drain; go.
  stage128(Ag, 0, &lds[0][0][0], tid);
  stage128(Bg, 0, &lds[0][1][0], tid);
  asm volatile("s_waitcnt vmcnt(0)" ::: "memory");
  BAR();

  for (int t = 0; t < NT; ++t) {
    const int b = t & 1;
    const signed char* At = &lds[b][0][0];
    const signed char* Bt = &lds[b][1][0];

    // Stage t+1 into the other buffer, issued at tile top: drain distance
    // ~= full tile (~5-6K cyc) >> HBM latency -> vmcnt(0) at tile end ~free.
    if (t + 1 < NT) {
      const size_t k1 = (size_t)(t + 1) * 128;
      stage128(Ag, k1, &lds[b ^ 1][0][0], tid);
      stage128(Bg, k1, &lds[b ^ 1][1][0], tid);
    }

    // Two K=64 sub-steps; per sub-step 12 frag reads + 32 MFMA (16x16x64,
    // the conflict-free pattern). Unpinned: compiler interleaves lgkmcnt.
#pragma unroll
    for (int kk = 0; kk < 2; ++kk) {
      v4i af[8], bf[4];
#pragma unroll
      for (int m = 0; m < 8; ++m)
        af[m] = frag128(At, wr * 128 + m * 16 + lr, kk * 4 + hi);
#pragma unroll
      for (int n = 0; n < 4; ++n)
        bf[n] = frag128(Bt, wc * 64 + n * 16 + lr, kk * 4 + hi);
#pragma unroll
      for (int m = 0; m < 8; ++m)
#pragma unroll
        for (int n = 0; n < 4; ++n)
          acc[m][n] = __builtin_amdgcn_mfma_i32_16x16x64_i8(af[m], bf[n], acc[m][n], 0, 0, 0);
    }

    // One sync point per 128-K tile: next tile fully landed.
    asm volatile("s_waitcnt vmcnt(0)" ::: "memory");
    BAR();
  }

  // ---- epilogue: y = acc * (sx[row]*scale) + bias.
  // C/D map (dtype-independent): col=lane&15, row=(lane>>4)*4+reg.
  const float s = scale_p[0];
  float bv[4];
#pragma unroll
  for (int n = 0; n < 4; ++n) bv[n] = bias[brow0 + wc * 64 + n * 16 + lr];
#pragma unroll
  for (int mi = 0; mi < 8; ++mi) {
    const int row0 = arow0 + wr * 128 + (mi >> 2) * 64 + (mi & 3) * 16 + hi * 4;
    float sc4[4];
#pragma unroll
    for (int j = 0; j < 4; ++j) sc4[j] = sx[row0 + j] * s;
#pragma unroll
    for (int n = 0; n < 4; ++n) {
      const int col = brow0 + wc * 64 + n * 16 + lr;
      const v4i v = acc[mi][n];
#pragma unroll
      for (int j = 0; j < 4; ++j)
        out[(size_t)(row0 + j) * N_TOT + col] = (float)v[j] * sc4[j] + bv[n];
    }
  }
}

// ---------------- fallback (no workspace): f16 DIRECT 128^2 kernel ----------------

__global__ __launch_bounds__(256) void gemm_direct(
    const float* __restrict__ Xf, const int* __restrict__ Wq,
    const float* __restrict__ scale_p, const float* __restrict__ bias,
    float* __restrict__ out)
{
  __shared__ _Float16 ldsA[128 * 64];
  __shared__ _Float16 ldsB[128 * 64];
  const int tid = threadIdx.x, lane = tid & 63, wave = tid >> 6;
  const int wr = wave >> 1, wc = wave & 1;
  const int bid = blockIdx.x;
  const int wg  = (bid & 7) * 512 + (bid >> 3);
  const int arow0 = (wg & 31) * 128, brow0 = (wg >> 5) * 128;
  f32x4 acc[4][4];
#pragma unroll
  for (int m = 0; m < 4; ++m)
#pragma unroll
    for (int n = 0; n < 4; ++n) acc[m][n] = (f32x4){0.f, 0.f, 0.f, 0.f};
  const int srow = tid >> 3, schunk = tid & 7;
  const int lr = lane & 15, hi = lane >> 4;
  for (int kt = 0; kt < K_TOT / 64; ++kt) {
    const size_t kbase = (size_t)kt * 64;
    __syncthreads();
#pragma unroll
    for (int i = 0; i < 4; ++i) {
      const int row = i * 32 + srow;
      const int p = schunk ^ (row & 7);
      const float* gx = Xf + (size_t)(arow0 + row) * K_TOT + kbase + schunk * 8;
      const int*   gw = Wq + (size_t)(brow0 + row) * K_TOT + kbase + schunk * 8;
      float4 x0 = ((const float4*)gx)[0];
      float4 x1 = ((const float4*)gx)[1];
      int4   w0 = ((const int4*)gw)[0];
      int4   w1 = ((const int4*)gw)[1];
      f16x8 ha = { (_Float16)x0.x, (_Float16)x0.y, (_Float16)x0.z, (_Float16)x0.w,
                   (_Float16)x1.x, (_Float16)x1.y, (_Float16)x1.z, (_Float16)x1.w };
      f16x8 hb = { (_Float16)w0.x, (_Float16)w0.y, (_Float16)w0.z, (_Float16)w0.w,
                   (_Float16)w1.x, (_Float16)w1.y, (_Float16)w1.z, (_Float16)w1.w };
      *(f16x8*)(ldsA + row * 64 + p * 8) = ha;
      *(f16x8*)(ldsB + row * 64 + p * 8) = hb;
    }
    __syncthreads();
#pragma unroll
    for (int s2 = 0; s2 < 2; ++s2) {
      f16x8 af2[4], bf2[4];
#pragma unroll
      for (int m = 0; m < 4; ++m) {
        const int r = wr * 64 + m * 16 + lr;
        af2[m] = *(const f16x8*)(ldsA + r * 64 + (((s2 * 4 + hi) ^ (r & 7)) * 8));
      }
#pragma unroll
      for (int n = 0; n < 4; ++n) {
        const int r = wc * 64 + n * 16 + lr;
        bf2[n] = *(const f16x8*)(ldsB + r * 64 + (((s2 * 4 + hi) ^ (r & 7)) * 8));
      }
#pragma unroll
      for (int m = 0; m < 4; ++m)
#pragma unroll
        for (int n = 0; n < 4; ++n)
          acc[m][n] = __builtin_amdgcn_mfma_f32_16x16x32_f16(af2[m], bf2[n], acc[m][n], 0, 0, 0);
    }
  }
  const float s = scale_p[0];
#pragma unroll
  for (int n = 0; n < 4; ++n) {
    const int col = brow0 + wc * 64 + n * 16 + lr;
    const float bvv = bias[col];
#pragma unroll
    for (int m = 0; m < 4; ++m) {
      const int row0 = arow0 + wr * 64 + m * 16 + hi * 4;
      const f32x4 v = acc[m][n];
#pragma unroll
      for (int j = 0; j < 4; ++j)
        out[(size_t)(row0 + j) * N_TOT + col] = v[j] * s + bvv;
    }
  }
}

// ---------------- launch ----------------

extern "C" void kernel_launch(void* const* d_in, const int* in_sizes, int n_in,
                              void* d_out, int out_size, void* d_ws, size_t ws_size,
                              hipStream_t stream) {
  const float* x     = (const float*)d_in[0];
  const int*   wq    = (const int*)d_in[1];
  const float* scale = (const float*)d_in[2];
  const float* bias  = (const float*)d_in[3];
  float*       out   = (float*)d_out;

  const size_t nA = (size_t)M_TOT * K_TOT;   // 16.7M
  const size_t nB = (size_t)N_TOT * K_TOT;   // 67.1M
  const size_t need = nA + nB + M_TOT * sizeof(float);  // ~84 MiB

  if (ws_size >= need) {
    signed char* A8 = (signed char*)d_ws;
    signed char* B8 = A8 + nA;
    float*       sx = (float*)(B8 + nB);
    cvt_x_i8<<<M_TOT, 256, 0, stream>>>(x, A8, sx);
    cvt_w_i8<<<2048, 256, 0, stream>>>(wq, B8, (int)(nB / 16));
    gemm_i8<<<(M_TOT / 256) * (N_TOT / 256), 512, 0, stream>>>(A8, B8, sx, scale, bias, out);
  } else {
    gemm_direct<<<(M_TOT / 128) * (N_TOT / 128), 256, 0, stream>>>(x, wq, scale, bias, out);
  }
}

// Round 15
// 404.352 us; speedup vs baseline: 1.0910x; 1.0156x over previous
//
#include <hip/hip_runtime.h>
#include <stdint.h>
#include <stddef.h>

// QuantizedColumnParallel: y[4096,16384] = x[4096,4096] @ (wq[16384,4096]*scale)^T + bias
// R15: GEMM = R14 unchanged (322us, within 3.5% of the pipes-sum floor that held
// across 7 schedule structures). Single change: cvt_x + cvt_w merged into ONE
// dispatch (x-pass overlaps under w-pass BW shadow, one less launch gap).

#define M_TOT 4096
#define N_TOT 16384
#define K_TOT 4096
#define NT    32          // K-tiles of 128

typedef __attribute__((ext_vector_type(4))) int      v4i;
typedef __attribute__((ext_vector_type(8))) _Float16 f16x8;
typedef __attribute__((ext_vector_type(4))) float    f32x4;

#define GLOAD_LDS16(g, l) __builtin_amdgcn_global_load_lds(                  \
    (const __attribute__((address_space(1))) void*)(g),                      \
    (__attribute__((address_space(3))) void*)(l), 16, 0, 0)

// ---------------- merged conversion pre-pass ----------------
// Blocks 0..4095: quantize one x row each (rowmax -> sx, f32 -> i8).
// Blocks 4096..6143: grid-stride pack w int32 -> i8 (16 elems/thread/iter).

__global__ __launch_bounds__(256) void cvt_both(const float* __restrict__ x,
                                                const int* __restrict__ w,
                                                signed char* __restrict__ ox,
                                                signed char* __restrict__ ow,
                                                float* __restrict__ sx, int n16) {
  const int tid = threadIdx.x;
  if (blockIdx.x < M_TOT) {
    const int row = blockIdx.x;
    const float* xr = x + (size_t)row * K_TOT;
    float4 v[4];
    float mx = 0.f;
#pragma unroll
    for (int j = 0; j < 4; ++j) {
      v[j] = ((const float4*)xr)[tid * 4 + j];
      mx = fmaxf(mx, fmaxf(fmaxf(fabsf(v[j].x), fabsf(v[j].y)),
                           fmaxf(fabsf(v[j].z), fabsf(v[j].w))));
    }
#pragma unroll
    for (int off = 32; off; off >>= 1) mx = fmaxf(mx, __shfl_xor(mx, off));
    __shared__ float wm[4];
    if ((tid & 63) == 0) wm[tid >> 6] = mx;
    __syncthreads();
    const float m4 = fmaxf(fmaxf(wm[0], wm[1]), fmaxf(wm[2], wm[3]));
    const float smax = fmaxf(m4, 1e-6f);
    const float inv  = 127.0f / smax;
    if (tid == 0) sx[row] = smax / 127.0f;
    int p[4];
#pragma unroll
    for (int j = 0; j < 4; ++j) {
      int q0 = (int)rintf(v[j].x * inv), q1 = (int)rintf(v[j].y * inv);
      int q2 = (int)rintf(v[j].z * inv), q3 = (int)rintf(v[j].w * inv);
      q0 = max(-127, min(127, q0)); q1 = max(-127, min(127, q1));
      q2 = max(-127, min(127, q2)); q3 = max(-127, min(127, q3));
      p[j] = (q0 & 255) | ((q1 & 255) << 8) | ((q2 & 255) << 16) | (q3 << 24);
    }
    ((int4*)(ox + (size_t)row * K_TOT))[tid] = make_int4(p[0], p[1], p[2], p[3]);
  } else {
    const int nblk   = gridDim.x - M_TOT;
    const int stride = nblk * 256;
    for (int i = (blockIdx.x - M_TOT) * 256 + tid; i < n16; i += stride) {
      int p[4];
#pragma unroll
      for (int j = 0; j < 4; ++j) {
        int4 a = ((const int4*)w)[i * 4 + j];
        p[j] = (a.x & 255) | ((a.y & 255) << 8) | ((a.z & 255) << 16) | (a.w << 24);
      }
      ((int4*)ow)[i] = make_int4(p[0], p[1], p[2], p[3]);
    }
  }
}

// ---------------- i8 GEMM: 256^2 tile, BK=128, 2 buffers, 1 sync/tile (R14) ----------------

__device__ __forceinline__ void stage128(const signed char* __restrict__ g,
                                         size_t kbyte, signed char* l, int tid) {
#pragma unroll
  for (int j = 0; j < 4; ++j) {
    const int ci  = j * 512 + tid;       // 0..2047 16B-chunks
    const int row = ci >> 3;             // 0..255
    const int sc  = (ci & 7) ^ (row & 7);
    GLOAD_LDS16(g + (size_t)row * K_TOT + kbyte + sc * 16, l + ci * 16);
  }
}

// Swizzled fragment read: row r, 16B chunk ch (0..7) of the 128B row.
__device__ __forceinline__ v4i frag128(const signed char* region, int r, int ch) {
  return *(const v4i*)(region + r * 128 + ((ch ^ (r & 7)) << 4));
}

#define BAR()    __builtin_amdgcn_s_barrier()

__global__ __launch_bounds__(512, 2) void gemm_i8(
    const signed char* __restrict__ A8, const signed char* __restrict__ B8,
    const float* __restrict__ sx, const float* __restrict__ scale_p,
    const float* __restrict__ bias, float* __restrict__ out)
{
  // lds[buf(2)][A=0|B=1][256*128 bytes] = 128 KiB -> 1 block/CU
  __shared__ __align__(16) signed char lds[2][2][32768];

  const int tid  = threadIdx.x;
  const int lane = tid & 63;
  const int wave = tid >> 6;
  const int wr = wave >> 2;            // 0..1 (M)
  const int wc = wave & 3;             // 0..3 (N)
  const int lr = lane & 15;
  const int hi = lane >> 4;            // 0..3 -> 16B sub-chunk of K=64

  // XCD-aware swizzle: 1024 wg, 8 XCDs, 128 contiguous per XCD; bm fast.
  const int bid = blockIdx.x;
  const int wg  = (bid & 7) * 128 + (bid >> 3);
  const int bm  = wg & 15;
  const int bn  = wg >> 4;
  const int arow0 = bm * 256;
  const int brow0 = bn * 256;

  const signed char* Ag = A8 + (size_t)arow0 * K_TOT;
  const signed char* Bg = B8 + (size_t)brow0 * K_TOT;

  v4i acc[8][4];
#pragma unroll
  for (int m = 0; m < 8; ++m)
#pragma unroll
    for (int n = 0; n < 4; ++n)
      acc[m][n] = (v4i){0, 0, 0, 0};

  // ---- prologue: stage tile0 -> buf0; drain; go.
  stage128(Ag, 0, &lds[0][0][0], tid);
  stage128(Bg, 0, &lds[0][1][0], tid);
  asm volatile("s_waitcnt vmcnt(0)" ::: "memory");
  BAR();

  for (int t = 0; t < NT; ++t) {
    const int b = t & 1;
    const signed char* At = &lds[b][0][0];
    const signed char* Bt = &lds[b][1][0];

    // Stage t+1 into the other buffer at tile top: drain distance ~= full tile
    // (~5-6K cyc) >> HBM latency -> vmcnt(0) at tile end ~free.
    if (t + 1 < NT) {
      const size_t k1 = (size_t)(t + 1) * 128;
      stage128(Ag, k1, &lds[b ^ 1][0][0], tid);
      stage128(Bg, k1, &lds[b ^ 1][1][0], tid);
    }

    // Two K=64 sub-steps; 12 frag reads + 32 MFMA each (conflict-free pattern).
#pragma unroll
    for (int kk = 0; kk < 2; ++kk) {
      v4i af[8], bf[4];
#pragma unroll
      for (int m = 0; m < 8; ++m)
        af[m] = frag128(At, wr * 128 + m * 16 + lr, kk * 4 + hi);
#pragma unroll
      for (int n = 0; n < 4; ++n)
        bf[n] = frag128(Bt, wc * 64 + n * 16 + lr, kk * 4 + hi);
#pragma unroll
      for (int m = 0; m < 8; ++m)
#pragma unroll
        for (int n = 0; n < 4; ++n)
          acc[m][n] = __builtin_amdgcn_mfma_i32_16x16x64_i8(af[m], bf[n], acc[m][n], 0, 0, 0);
    }

    // One sync point per 128-K tile: next tile fully landed.
    asm volatile("s_waitcnt vmcnt(0)" ::: "memory");
    BAR();
  }

  // ---- epilogue: y = acc * (sx[row]*scale) + bias.
  // C/D map (dtype-independent): col=lane&15, row=(lane>>4)*4+reg.
  const float s = scale_p[0];
  float bv[4];
#pragma unroll
  for (int n = 0; n < 4; ++n) bv[n] = bias[brow0 + wc * 64 + n * 16 + lr];
#pragma unroll
  for (int mi = 0; mi < 8; ++mi) {
    const int row0 = arow0 + wr * 128 + (mi >> 2) * 64 + (mi & 3) * 16 + hi * 4;
    float sc4[4];
#pragma unroll
    for (int j = 0; j < 4; ++j) sc4[j] = sx[row0 + j] * s;
#pragma unroll
    for (int n = 0; n < 4; ++n) {
      const int col = brow0 + wc * 64 + n * 16 + lr;
      const v4i v = acc[mi][n];
#pragma unroll
      for (int j = 0; j < 4; ++j)
        out[(size_t)(row0 + j) * N_TOT + col] = (float)v[j] * sc4[j] + bv[n];
    }
  }
}

// ---------------- fallback (no workspace): f16 DIRECT 128^2 kernel ----------------

__global__ __launch_bounds__(256) void gemm_direct(
    const float* __restrict__ Xf, const int* __restrict__ Wq,
    const float* __restrict__ scale_p, const float* __restrict__ bias,
    float* __restrict__ out)
{
  __shared__ _Float16 ldsA[128 * 64];
  __shared__ _Float16 ldsB[128 * 64];
  const int tid = threadIdx.x, lane = tid & 63, wave = tid >> 6;
  const int wr = wave >> 1, wc = wave & 1;
  const int bid = blockIdx.x;
  const int wg  = (bid & 7) * 512 + (bid >> 3);
  const int arow0 = (wg & 31) * 128, brow0 = (wg >> 5) * 128;
  f32x4 acc[4][4];
#pragma unroll
  for (int m = 0; m < 4; ++m)
#pragma unroll
    for (int n = 0; n < 4; ++n) acc[m][n] = (f32x4){0.f, 0.f, 0.f, 0.f};
  const int srow = tid >> 3, schunk = tid & 7;
  const int lr = lane & 15, hi = lane >> 4;
  for (int kt = 0; kt < K_TOT / 64; ++kt) {
    const size_t kbase = (size_t)kt * 64;
    __syncthreads();
#pragma unroll
    for (int i = 0; i < 4; ++i) {
      const int row = i * 32 + srow;
      const int p = schunk ^ (row & 7);
      const float* gx = Xf + (size_t)(arow0 + row) * K_TOT + kbase + schunk * 8;
      const int*   gw = Wq + (size_t)(brow0 + row) * K_TOT + kbase + schunk * 8;
      float4 x0 = ((const float4*)gx)[0];
      float4 x1 = ((const float4*)gx)[1];
      int4   w0 = ((const int4*)gw)[0];
      int4   w1 = ((const int4*)gw)[1];
      f16x8 ha = { (_Float16)x0.x, (_Float16)x0.y, (_Float16)x0.z, (_Float16)x0.w,
                   (_Float16)x1.x, (_Float16)x1.y, (_Float16)x1.z, (_Float16)x1.w };
      f16x8 hb = { (_Float16)w0.x, (_Float16)w0.y, (_Float16)w0.z, (_Float16)w0.w,
                   (_Float16)w1.x, (_Float16)w1.y, (_Float16)w1.z, (_Float16)w1.w };
      *(f16x8*)(ldsA + row * 64 + p * 8) = ha;
      *(f16x8*)(ldsB + row * 64 + p * 8) = hb;
    }
    __syncthreads();
#pragma unroll
    for (int s2 = 0; s2 < 2; ++s2) {
      f16x8 af2[4], bf2[4];
#pragma unroll
      for (int m = 0; m < 4; ++m) {
        const int r = wr * 64 + m * 16 + lr;
        af2[m] = *(const f16x8*)(ldsA + r * 64 + (((s2 * 4 + hi) ^ (r & 7)) * 8));
      }
#pragma unroll
      for (int n = 0; n < 4; ++n) {
        const int r = wc * 64 + n * 16 + lr;
        bf2[n] = *(const f16x8*)(ldsB + r * 64 + (((s2 * 4 + hi) ^ (r & 7)) * 8));
      }
#pragma unroll
      for (int m = 0; m < 4; ++m)
#pragma unroll
        for (int n = 0; n < 4; ++n)
          acc[m][n] = __builtin_amdgcn_mfma_f32_16x16x32_f16(af2[m], bf2[n], acc[m][n], 0, 0, 0);
    }
  }
  const float s = scale_p[0];
#pragma unroll
  for (int n = 0; n < 4; ++n) {
    const int col = brow0 + wc * 64 + n * 16 + lr;
    const float bvv = bias[col];
#pragma unroll
    for (int m = 0; m < 4; ++m) {
      const int row0 = arow0 + wr * 64 + m * 16 + hi * 4;
      const f32x4 v = acc[m][n];
#pragma unroll
      for (int j = 0; j < 4; ++j)
        out[(size_t)(row0 + j) * N_TOT + col] = v[j] * s + bvv;
    }
  }
}

// ---------------- launch ----------------

extern "C" void kernel_launch(void* const* d_in, const int* in_sizes, int n_in,
                              void* d_out, int out_size, void* d_ws, size_t ws_size,
                              hipStream_t stream) {
  const float* x     = (const float*)d_in[0];
  const int*   wq    = (const int*)d_in[1];
  const float* scale = (const float*)d_in[2];
  const float* bias  = (const float*)d_in[3];
  float*       out   = (float*)d_out;

  const size_t nA = (size_t)M_TOT * K_TOT;   // 16.7M
  const size_t nB = (size_t)N_TOT * K_TOT;   // 67.1M
  const size_t need = nA + nB + M_TOT * sizeof(float);  // ~84 MiB

  if (ws_size >= need) {
    signed char* A8 = (signed char*)d_ws;
    signed char* B8 = A8 + nA;
    float*       sx = (float*)(B8 + nB);
    cvt_both<<<M_TOT + 2048, 256, 0, stream>>>(x, wq, A8, B8, sx, (int)(nB / 16));
    gemm_i8<<<(M_TOT / 256) * (N_TOT / 256), 512, 0, stream>>>(A8, B8, sx, scale, bias, out);
  } else {
    gemm_direct<<<(M_TOT / 128) * (N_TOT / 128), 256, 0, stream>>>(x, wq, scale, bias, out);
  }
}